// Round 8
// baseline (897.599 us; speedup 1.0000x reference)
//
#include <hip/hip_runtime.h>

// ---------------------------------------------------------------------------
// GNN predictor (fp32 I/O). Round 8 structure:
//   prep_weights   : repack weights; w1pos; bf16 MFMA B-frags for W2e
//   k_phase1       : bucket-scatter edges into 256-node buckets (LDS hist,
//                    contiguous runs) + precompute_A (bf16 rows) in one grid
//   k_bucket_fused : ONE block per bucket:
//                      - 16-edge MFMA batches straight from pairbuf
//                      - tanh -> ds_add_f32 into 64KB LDS sum tile
//                        (bank-rotated addressing)
//                      - barrier, then node MLP reading sum_h from LDS,
//                        writes d_out directly.
//   (k_bucketB, ssrc, sumh, node_kernel all eliminated)
// ---------------------------------------------------------------------------

#define LRELU_SLOPE 0.01f
#define BUCK_SHIFT 8                  // 256 nodes per bucket

constexpr int OFF_W1ET  = 0;          // [32][76]
constexpr int OFF_B1E   = 2432;       // [32]
constexpr int OFF_W2E   = 2464;       // [32][64]
constexpr int OFF_B2E   = 4512;       // [64]
constexpr int OFF_W1NT  = 4576;       // [32][138]
constexpr int OFF_B1N   = 8992;       // [32]
constexpr int OFF_W2N   = 9024;       // [32][64]
constexpr int OFF_B2N   = 11072;      // [64]
constexpr int OFF_W1POS = 11136;      // [32] float2 (W1e rows 2,3)
constexpr int W_TOTAL   = 11200;

typedef __bf16 bf16x8 __attribute__((ext_vector_type(8)));
typedef float  f32x4  __attribute__((ext_vector_type(4)));

__device__ __forceinline__ float ftanh(float x) {
    float e = __builtin_amdgcn_exp2f(x * 2.8853900817779268f);
    return 1.0f - 2.0f * __builtin_amdgcn_rcpf(e + 1.0f);
}
__device__ __forceinline__ unsigned f2bf_pair(float f0, float f1) {
    unsigned u0 = __float_as_uint(f0), u1 = __float_as_uint(f1);
    unsigned r0 = (u0 + 0x7fffu + ((u0 >> 16) & 1u)) >> 16;   // RNE
    unsigned r1 = (u1 + 0x7fffu + ((u1 >> 16) & 1u)) >> 16;
    return r0 | (r1 << 16);
}
__device__ __forceinline__ float bf_lo(unsigned p) { return __uint_as_float(p << 16); }
__device__ __forceinline__ float bf_hi(unsigned p) { return __uint_as_float(p & 0xffff0000u); }

// ---------------------------------------------------------------------------
__global__ void prep_weights(const float* __restrict__ W1e, const float* __restrict__ b1e,
                             const float* __restrict__ W2e, const float* __restrict__ b2e,
                             const float* __restrict__ W1n, const float* __restrict__ b1n,
                             const float* __restrict__ W2n, const float* __restrict__ b2n,
                             float* __restrict__ Wf, uint4* __restrict__ fragW2) {
    int t = blockIdx.x * blockDim.x + threadIdx.x;
    int T = gridDim.x * blockDim.x;
    for (int idx = t; idx < 2432; idx += T) {            // W1e [76][32] -> [32][76]
        int i = idx / 32, j = idx % 32;
        Wf[OFF_W1ET + j * 76 + i] = W1e[idx];
    }
    for (int idx = t; idx < 32; idx += T)   Wf[OFF_B1E + idx] = b1e[idx];
    for (int idx = t; idx < 2048; idx += T) Wf[OFF_W2E + idx] = W2e[idx];
    for (int idx = t; idx < 64; idx += T)   Wf[OFF_B2E + idx] = b2e[idx];
    for (int idx = t; idx < 4416; idx += T) {            // W1n [138][32] -> [32][138]
        int i = idx / 32, j = idx % 32;
        Wf[OFF_W1NT + j * 138 + i] = W1n[idx];
    }
    for (int idx = t; idx < 32; idx += T)   Wf[OFF_B1N + idx] = b1n[idx];
    for (int idx = t; idx < 2048; idx += T) Wf[OFF_W2N + idx] = W2n[idx];
    for (int idx = t; idx < 64; idx += T)   Wf[OFF_B2N + idx] = b2n[idx];
    for (int idx = t; idx < 32; idx += T) {
        Wf[OFF_W1POS + 2 * idx + 0] = W1e[2 * 32 + idx];
        Wf[OFF_W1POS + 2 * idx + 1] = W1e[3 * 32 + idx];
    }
    // MFMA B-fragments for W2e (bf16), 4 N-tiles x 64 lanes x 16B
    for (int idx = t; idx < 256; idx += T) {
        int tt = idx >> 6, l = idx & 63;
        int colv = l & 15, quadv = l >> 4;
        uint4 v;
        unsigned pk[4];
#pragma unroll
        for (int pr = 0; pr < 4; pr++) {
            int j0 = quadv * 8 + 2 * pr;
            float f0 = W2e[j0 * 64 + 16 * tt + colv];
            float f1 = W2e[(j0 + 1) * 64 + 16 * tt + colv];
            pk[pr] = f2bf_pair(f0, f1);
        }
        v.x = pk[0]; v.y = pk[1]; v.z = pk[2]; v.w = pk[3];
        fragW2[tt * 64 + l] = v;
    }
}

// ---------------------------------------------------------------------------
// Phase 1: bucket-scatter (blocks < nblkA) + precompute_A (remaining blocks)
// pairbuf entry: src | (dst&255)<<20
// ---------------------------------------------------------------------------
__global__ __launch_bounds__(256) void k_phase1(
    const float* __restrict__ hbuf, const float* __restrict__ ubuf,
    const float* __restrict__ posbuf, const float* __restrict__ Wf,
    uint4* __restrict__ Abf,
    const int* __restrict__ src, const int* __restrict__ dst,
    int* __restrict__ gcnt, unsigned* __restrict__ pairbuf,
    int E, int N, int C, int nblkA) {
    __shared__ int cnt[512], base[512];
    int tid = threadIdx.x;
    if ((int)blockIdx.x < nblkA) {
        for (int i = tid; i < 512; i += 256) cnt[i] = 0;
        __syncthreads();
        int e0 = blockIdx.x * 4096;
#pragma unroll
        for (int k = 0; k < 16; k++) {
            int e = e0 + k * 256 + tid;
            if (e < E) atomicAdd(&cnt[dst[e] >> BUCK_SHIFT], 1);
        }
        __syncthreads();
        for (int i = tid; i < 512; i += 256) {
            int c = cnt[i];
            base[i] = (c > 0) ? atomicAdd(&gcnt[i], c) : 0;
            cnt[i] = 0;
        }
        __syncthreads();
#pragma unroll
        for (int k = 0; k < 16; k++) {
            int e = e0 + k * 256 + tid;
            if (e < E) {
                int d = dst[e];
                int b = d >> BUCK_SHIFT;
                int r = base[b] + atomicAdd(&cnt[b], 1);
                if (r < C)
                    pairbuf[(size_t)b * C + r] =
                        (unsigned)src[e] | ((unsigned)(d & 255) << 20);
            }
        }
        return;
    }
    // ---- precompute_A part ----
    int n = (blockIdx.x - nblkA) * 256 + tid;
    if (n >= N) return;
    float x[76];
    float2 pp = ((const float2*)posbuf)[n];
    x[0] = pp.x; x[1] = pp.y; x[2] = 0.f; x[3] = 0.f;
    const float4* u4 = (const float4*)ubuf;
#pragma unroll
    for (int c = 0; c < 2; c++) {
        float4 uu = u4[(size_t)n * 2 + c];
        int b = 4 + 4 * c;
        x[b] = uu.x; x[b + 1] = uu.y; x[b + 2] = uu.z; x[b + 3] = uu.w;
    }
    const float4* h4 = (const float4*)hbuf;
#pragma unroll
    for (int c = 0; c < 16; c++) {
        float4 hh = h4[(size_t)n * 16 + c];
        int b = 12 + 4 * c;
        x[b] = hh.x; x[b + 1] = hh.y; x[b + 2] = hh.z; x[b + 3] = hh.w;
    }
    float ar[32];
#pragma unroll 1
    for (int j = 0; j < 32; j++) {
        const float* w1 = Wf + OFF_W1ET + j * 76;
        float a0 = Wf[OFF_B1E + j], a1 = 0.f, a2 = 0.f, a3 = 0.f;
#pragma unroll
        for (int i = 0; i < 76; i += 4) {
            a0 = fmaf(x[i + 0], w1[i + 0], a0);
            a1 = fmaf(x[i + 1], w1[i + 1], a1);
            a2 = fmaf(x[i + 2], w1[i + 2], a2);
            a3 = fmaf(x[i + 3], w1[i + 3], a3);
        }
        ar[j] = (a0 + a1) + (a2 + a3);
    }
#pragma unroll
    for (int c = 0; c < 4; c++) {
        uint4 v;
        v.x = f2bf_pair(ar[8 * c + 0], ar[8 * c + 1]);
        v.y = f2bf_pair(ar[8 * c + 2], ar[8 * c + 3]);
        v.z = f2bf_pair(ar[8 * c + 4], ar[8 * c + 5]);
        v.w = f2bf_pair(ar[8 * c + 6], ar[8 * c + 7]);
        Abf[(size_t)n * 4 + c] = v;
    }
}

// ---------------------------------------------------------------------------
// Fused bucket kernel: edge MLP + LDS scatter-sum + node MLP. One block per
// 256-node bucket; 64KB LDS sum tile, bank-rotated addr (c+node)&63.
// ---------------------------------------------------------------------------
__global__ __launch_bounds__(256, 2) void k_bucket_fused(
    const unsigned* __restrict__ pairbuf, const int* __restrict__ gcnt,
    const uint4* __restrict__ Abf, const float* __restrict__ posbuf,
    const float* __restrict__ Wf, const uint4* __restrict__ fragW2,
    const float* __restrict__ hbuf, const float* __restrict__ ubuf,
    float* __restrict__ out, int N, int C) {
    __shared__ float tile[256 * 64];    // 64 KB sum_h tile
    int b = blockIdx.x, tid = threadIdx.x;
    int lane = tid & 63, wave = tid >> 6;
    int col = lane & 15, quad = lane >> 4;
    int cntb = gcnt[b]; cntb = (cntb < C) ? cntb : C;

    for (int i = tid; i < 256 * 64; i += 256) tile[i] = 0.f;

    // wave-resident W2 fragments / bias / pos-row weights
    union { uint4 u; bf16x8 v; } cvt;
    bf16x8 bfr[4];
#pragma unroll
    for (int t = 0; t < 4; t++) { cvt.u = fragW2[t * 64 + lane]; bfr[t] = cvt.v; }
    float c0[4];
#pragma unroll
    for (int t = 0; t < 4; t++) c0[t] = Wf[OFF_B2E + 16 * t + col];
    float wx[8], wy[8];
#pragma unroll
    for (int jj = 0; jj < 8; jj++) {
        float2 wv = ((const float2*)(Wf + OFF_W1POS))[quad * 8 + jj];
        wx[jj] = wv.x; wy[jj] = wv.y;
    }
    __syncthreads();

    size_t pbase = (size_t)b * C;
    int nb = (cntb + 15) >> 4;
#pragma unroll 1
    for (int ib = wave; ib < nb; ib += 4) {
        int base = ib * 16;
        int m = cntb - base; m = (m < 16) ? m : 16;
        int idx = base + ((col < m) ? col : (m - 1));
        unsigned pair = pairbuf[pbase + idx];
        int s  = (int)(pair & 0xFFFFFu);
        int dl = (int)((pair >> 20) & 255u);
        float2 pd = ((const float2*)posbuf)[(b << BUCK_SHIFT) + dl];
        uint4 ar = Abf[(size_t)s * 4 + quad];

        bf16x8 af;
        {
            float v0 = fmaf(pd.x, wx[0], fmaf(pd.y, wy[0], bf_lo(ar.x)));
            float v1 = fmaf(pd.x, wx[1], fmaf(pd.y, wy[1], bf_hi(ar.x)));
            float v2 = fmaf(pd.x, wx[2], fmaf(pd.y, wy[2], bf_lo(ar.y)));
            float v3 = fmaf(pd.x, wx[3], fmaf(pd.y, wy[3], bf_hi(ar.y)));
            float v4 = fmaf(pd.x, wx[4], fmaf(pd.y, wy[4], bf_lo(ar.z)));
            float v5 = fmaf(pd.x, wx[5], fmaf(pd.y, wy[5], bf_hi(ar.z)));
            float v6 = fmaf(pd.x, wx[6], fmaf(pd.y, wy[6], bf_lo(ar.w)));
            float v7 = fmaf(pd.x, wx[7], fmaf(pd.y, wy[7], bf_hi(ar.w)));
            v0 = fmaxf(v0, LRELU_SLOPE * v0); v1 = fmaxf(v1, LRELU_SLOPE * v1);
            v2 = fmaxf(v2, LRELU_SLOPE * v2); v3 = fmaxf(v3, LRELU_SLOPE * v3);
            v4 = fmaxf(v4, LRELU_SLOPE * v4); v5 = fmaxf(v5, LRELU_SLOPE * v5);
            v6 = fmaxf(v6, LRELU_SLOPE * v6); v7 = fmaxf(v7, LRELU_SLOPE * v7);
            af[0] = (__bf16)v0; af[1] = (__bf16)v1; af[2] = (__bf16)v2; af[3] = (__bf16)v3;
            af[4] = (__bf16)v4; af[5] = (__bf16)v5; af[6] = (__bf16)v6; af[7] = (__bf16)v7;
        }
        // dst-local of the 4 D-rows this lane owns (row = quad*4+r)
        int dlr[4];
#pragma unroll
        for (int r = 0; r < 4; r++) {
            int pr = __shfl((int)pair, quad * 4 + r);
            dlr[r] = (pr >> 20) & 255;
        }
#pragma unroll
        for (int t = 0; t < 4; t++) {
            f32x4 acc = {c0[t], c0[t], c0[t], c0[t]};
            acc = __builtin_amdgcn_mfma_f32_16x16x32_bf16(af, bfr[t], acc, 0, 0, 0);
            int c = 16 * t + col;
#pragma unroll
            for (int r = 0; r < 4; r++) {
                if (quad * 4 + r < m) {
                    int addr = dlr[r] * 64 + ((c + dlr[r]) & 63);   // bank-rotated
                    unsafeAtomicAdd(&tile[addr], ftanh(acc[r]));
                }
            }
        }
    }
    __syncthreads();

    // ---- node MLP phase: thread tid owns node (b<<8)+tid ----
    int n = (b << BUCK_SHIFT) + tid;
    if (n >= N) return;

    float x[138];
    {
        float2 pp = ((const float2*)posbuf)[n];
        x[0] = pp.x; x[1] = pp.y;
        const float4* h4 = (const float4*)hbuf;
#pragma unroll
        for (int c = 0; c < 16; c++) {
            float4 hh = h4[(size_t)n * 16 + c];
            int bq = 2 + 4 * c;
            x[bq] = hh.x; x[bq + 1] = hh.y; x[bq + 2] = hh.z; x[bq + 3] = hh.w;
        }
#pragma unroll 1
        for (int k = 0; k < 64; k++)                         // sum_h from LDS
            x[66 + k] = tile[tid * 64 + ((k + tid) & 63)];   // conflict-free
        const float4* u4 = (const float4*)ubuf;
#pragma unroll
        for (int c = 0; c < 2; c++) {
            float4 uu = u4[(size_t)n * 2 + c];
            int bq = 130 + 4 * c;
            x[bq] = uu.x; x[bq + 1] = uu.y; x[bq + 2] = uu.z; x[bq + 3] = uu.w;
        }
    }

    float o[64];
#pragma unroll
    for (int k = 0; k < 64; k++) o[k] = Wf[OFF_B2N + k];

#pragma unroll 1
    for (int j = 0; j < 32; j++) {
        const float* w1 = Wf + OFF_W1NT + j * 138;
        float a0 = Wf[OFF_B1N + j], a1 = 0.f, a2 = 0.f, a3 = 0.f;
#pragma unroll
        for (int i = 0; i < 136; i += 4) {
            a0 = fmaf(x[i + 0], w1[i + 0], a0);
            a1 = fmaf(x[i + 1], w1[i + 1], a1);
            a2 = fmaf(x[i + 2], w1[i + 2], a2);
            a3 = fmaf(x[i + 3], w1[i + 3], a3);
        }
        a0 = fmaf(x[136], w1[136], a0);
        a1 = fmaf(x[137], w1[137], a1);
        float a = (a0 + a1) + (a2 + a3);
        a = (a >= 0.f) ? a : LRELU_SLOPE * a;
        const float* w2 = Wf + OFF_W2N + j * 64;
#pragma unroll
        for (int k = 0; k < 64; k++) o[k] = fmaf(a, w2[k], o[k]);
    }

    float4* orow = (float4*)(out + (size_t)n * 64);
#pragma unroll
    for (int c = 0; c < 16; c++) {
        float4 v;
        v.x = ftanh(o[4 * c + 0]); v.y = ftanh(o[4 * c + 1]);
        v.z = ftanh(o[4 * c + 2]); v.w = ftanh(o[4 * c + 3]);
        orow[c] = v;
    }
}

// ---------------------------------------------------------------------------
extern "C" void kernel_launch(void* const* d_in, const int* in_sizes, int n_in,
                              void* d_out, int out_size, void* d_ws, size_t ws_size,
                              hipStream_t stream) {
    const float* hbuf   = (const float*)d_in[0];
    const float* ubuf   = (const float*)d_in[1];
    const float* posbuf = (const float*)d_in[2];
    const int* src = (const int*)d_in[3];
    const int* dst = (const int*)d_in[4];

    int N = in_sizes[0] / 64;
    int E = in_sizes[3];
    int NBUCK = (N + 255) >> BUCK_SHIFT;                 // 256-node buckets
    int C = ((2 * ((E + NBUCK - 1) / NBUCK)) + 255) & ~255;  // bucket capacity
    int nblkA = (E + 4095) / 4096;

    char* p = (char*)d_ws;
    auto alloc = [&](size_t bytes) {
        char* r = p;
        p += (bytes + 255) & ~(size_t)255;
        return r;
    };
    float*    Wf      = (float*)alloc(W_TOTAL * 4);
    uint4*    fragW2  = (uint4*)alloc(4 * 64 * 16);
    uint4*    Abf     = (uint4*)alloc((size_t)N * 64);   // bf16 A rows, 64B
    int*      gcnt    = (int*)alloc((size_t)NBUCK * 4);
    unsigned* pairbuf = (unsigned*)alloc((size_t)NBUCK * C * 4);

    prep_weights<<<32, 256, 0, stream>>>(
        (const float*)d_in[5], (const float*)d_in[6],
        (const float*)d_in[7], (const float*)d_in[8],
        (const float*)d_in[9], (const float*)d_in[10],
        (const float*)d_in[11], (const float*)d_in[12], Wf, fragW2);

    hipMemsetAsync(gcnt, 0, (size_t)NBUCK * 4, stream);

    int nblkP = nblkA + (N + 255) / 256;
    k_phase1<<<nblkP, 256, 0, stream>>>(
        hbuf, ubuf, posbuf, Wf, Abf, src, dst, gcnt, pairbuf, E, N, C, nblkA);

    k_bucket_fused<<<NBUCK, 256, 0, stream>>>(
        pairbuf, gcnt, Abf, posbuf, Wf, fragW2, hbuf, ubuf,
        (float*)d_out, N, C);
}

// Round 9
// 305.207 us; speedup vs baseline: 2.9410x; 2.9410x over previous
//
#include <hip/hip_runtime.h>

// ---------------------------------------------------------------------------
// GNN predictor (fp32 I/O). Round 9 = Round 7 structure (best: 306us) plus:
//   - A2[n][32]: pos/h/u part of NODE MLP layer-1 precomputed in k_phase1
//     (node kernel drops x[138] -> much lower VGPR, 4096 FMA/node)
//   - fused_edge_gather: manual prefetch of next batch's ssrc/Abf
// Round-8's 64KB-LDS bucket fusion REGRESSED 3x (391 blocks = 6 waves/CU,
// latency exposed); do not re-fuse below ~8 waves/CU.
// ---------------------------------------------------------------------------

#define LRELU_SLOPE 0.01f
#define BUCK_SHIFT 8                  // 256 nodes per bucket

constexpr int OFF_W1ET  = 0;          // [32][76]  edge W1 transposed
constexpr int OFF_B1E   = 2432;       // [32]
constexpr int OFF_W2E   = 2464;       // [32][64]
constexpr int OFF_B2E   = 4512;       // [64]
constexpr int OFF_W1NA  = 4576;       // [32][76]  node W1 (pos,u,h dims) in x76 order
constexpr int OFF_W1NS  = 7008;       // [32][64]  node W1 (sumh dims) transposed
constexpr int OFF_W2N   = 9056;       // [32][64]
constexpr int OFF_B2N   = 11104;      // [64]
constexpr int OFF_B1N   = 11168;      // [32]
constexpr int OFF_W1POS = 11200;      // [32] float2 (W1e rows 2,3)
constexpr int W_TOTAL   = 11264;

typedef __bf16 bf16x8 __attribute__((ext_vector_type(8)));
typedef float  f32x4  __attribute__((ext_vector_type(4)));

__device__ __forceinline__ float ftanh(float x) {
    float e = __builtin_amdgcn_exp2f(x * 2.8853900817779268f);
    return 1.0f - 2.0f * __builtin_amdgcn_rcpf(e + 1.0f);
}
__device__ __forceinline__ unsigned f2bf_pair(float f0, float f1) {
    unsigned u0 = __float_as_uint(f0), u1 = __float_as_uint(f1);
    unsigned r0 = (u0 + 0x7fffu + ((u0 >> 16) & 1u)) >> 16;   // RNE
    unsigned r1 = (u1 + 0x7fffu + ((u1 >> 16) & 1u)) >> 16;
    return r0 | (r1 << 16);
}
__device__ __forceinline__ float bf_lo(unsigned p) { return __uint_as_float(p << 16); }
__device__ __forceinline__ float bf_hi(unsigned p) { return __uint_as_float(p & 0xffff0000u); }

// ---------------------------------------------------------------------------
__global__ void prep_weights(const float* __restrict__ W1e, const float* __restrict__ b1e,
                             const float* __restrict__ W2e, const float* __restrict__ b2e,
                             const float* __restrict__ W1n, const float* __restrict__ b1n,
                             const float* __restrict__ W2n, const float* __restrict__ b2n,
                             float* __restrict__ Wf, uint4* __restrict__ fragW2) {
    int t = blockIdx.x * blockDim.x + threadIdx.x;
    int T = gridDim.x * blockDim.x;
    for (int idx = t; idx < 2432; idx += T) {            // W1e [76][32] -> [32][76]
        int i = idx / 32, j = idx % 32;
        Wf[OFF_W1ET + j * 76 + i] = W1e[idx];
    }
    for (int idx = t; idx < 32; idx += T)   Wf[OFF_B1E + idx] = b1e[idx];
    for (int idx = t; idx < 2048; idx += T) Wf[OFF_W2E + idx] = W2e[idx];
    for (int idx = t; idx < 64; idx += T)   Wf[OFF_B2E + idx] = b2e[idx];
    // W1NA[j][i]: node-layer1 weights for x76 = [pos(2),0,0,u(8),h(64)]
    // node input order: pos rows 0-1, h rows 2-65, sumh rows 66-129, u rows 130-137
    for (int idx = t; idx < 2432; idx += T) {
        int j = idx / 76, i = idx % 76;
        float v = 0.f;
        if (i < 2)                 v = W1n[i * 32 + j];
        else if (i >= 4 && i < 12) v = W1n[(130 + (i - 4)) * 32 + j];
        else if (i >= 12)          v = W1n[(2 + (i - 12)) * 32 + j];
        Wf[OFF_W1NA + idx] = v;
    }
    for (int idx = t; idx < 2048; idx += T) {            // W1NS [32][64]
        int j = idx / 64, k = idx % 64;
        Wf[OFF_W1NS + idx] = W1n[(66 + k) * 32 + j];
    }
    for (int idx = t; idx < 2048; idx += T) Wf[OFF_W2N + idx] = W2n[idx];
    for (int idx = t; idx < 64; idx += T)   Wf[OFF_B2N + idx] = b2n[idx];
    for (int idx = t; idx < 32; idx += T)   Wf[OFF_B1N + idx] = b1n[idx];
    for (int idx = t; idx < 32; idx += T) {
        Wf[OFF_W1POS + 2 * idx + 0] = W1e[2 * 32 + idx];
        Wf[OFF_W1POS + 2 * idx + 1] = W1e[3 * 32 + idx];
    }
    // MFMA B-fragments for W2e (bf16), 4 N-tiles x 64 lanes x 16B
    for (int idx = t; idx < 256; idx += T) {
        int tt = idx >> 6, l = idx & 63;
        int colv = l & 15, quadv = l >> 4;
        uint4 v;
        unsigned pk[4];
#pragma unroll
        for (int pr = 0; pr < 4; pr++) {
            int j0 = quadv * 8 + 2 * pr;
            float f0 = W2e[j0 * 64 + 16 * tt + colv];
            float f1 = W2e[(j0 + 1) * 64 + 16 * tt + colv];
            pk[pr] = f2bf_pair(f0, f1);
        }
        v.x = pk[0]; v.y = pk[1]; v.z = pk[2]; v.w = pk[3];
        fragW2[tt * 64 + l] = v;
    }
}

// ---------------------------------------------------------------------------
// Phase 1: bucket-scatter (blocks < nblkA) + per-node precompute (rest):
//   Abf[n][32] bf16 : edge-MLP layer1 src part
//   A2 [n][32] f32  : node-MLP layer1 pos/h/u part (+b1n)
// ---------------------------------------------------------------------------
__global__ __launch_bounds__(256) void k_phase1(
    const float* __restrict__ hbuf, const float* __restrict__ ubuf,
    const float* __restrict__ posbuf, const float* __restrict__ Wf,
    uint4* __restrict__ Abf, float* __restrict__ A2,
    const int* __restrict__ src, const int* __restrict__ dst,
    int* __restrict__ gcnt, unsigned* __restrict__ pairbuf,
    int E, int N, int C, int nblkA) {
    __shared__ int cnt[512], base[512];
    int tid = threadIdx.x;
    if ((int)blockIdx.x < nblkA) {
        for (int i = tid; i < 512; i += 256) cnt[i] = 0;
        __syncthreads();
        int e0 = blockIdx.x * 4096;
#pragma unroll
        for (int k = 0; k < 16; k++) {
            int e = e0 + k * 256 + tid;
            if (e < E) atomicAdd(&cnt[dst[e] >> BUCK_SHIFT], 1);
        }
        __syncthreads();
        for (int i = tid; i < 512; i += 256) {
            int c = cnt[i];
            base[i] = (c > 0) ? atomicAdd(&gcnt[i], c) : 0;
            cnt[i] = 0;
        }
        __syncthreads();
#pragma unroll
        for (int k = 0; k < 16; k++) {
            int e = e0 + k * 256 + tid;
            if (e < E) {
                int d = dst[e];
                int b = d >> BUCK_SHIFT;
                int r = base[b] + atomicAdd(&cnt[b], 1);
                if (r < C)
                    pairbuf[(size_t)b * C + r] =
                        (unsigned)src[e] | ((unsigned)(d & 255) << 20);
            }
        }
        return;
    }
    // ---- per-node precompute ----
    int n = (blockIdx.x - nblkA) * 256 + tid;
    if (n >= N) return;
    float x[76];
    float2 pp = ((const float2*)posbuf)[n];
    x[0] = pp.x; x[1] = pp.y; x[2] = 0.f; x[3] = 0.f;
    const float4* u4 = (const float4*)ubuf;
#pragma unroll
    for (int c = 0; c < 2; c++) {
        float4 uu = u4[(size_t)n * 2 + c];
        int b = 4 + 4 * c;
        x[b] = uu.x; x[b + 1] = uu.y; x[b + 2] = uu.z; x[b + 3] = uu.w;
    }
    const float4* h4 = (const float4*)hbuf;
#pragma unroll
    for (int c = 0; c < 16; c++) {
        float4 hh = h4[(size_t)n * 16 + c];
        int b = 12 + 4 * c;
        x[b] = hh.x; x[b + 1] = hh.y; x[b + 2] = hh.z; x[b + 3] = hh.w;
    }
    float ar[32];
#pragma unroll 1
    for (int j = 0; j < 32; j++) {
        const float* w1 = Wf + OFF_W1ET + j * 76;
        float a0 = Wf[OFF_B1E + j], a1 = 0.f, a2 = 0.f, a3 = 0.f;
#pragma unroll
        for (int i = 0; i < 76; i += 4) {
            a0 = fmaf(x[i + 0], w1[i + 0], a0);
            a1 = fmaf(x[i + 1], w1[i + 1], a1);
            a2 = fmaf(x[i + 2], w1[i + 2], a2);
            a3 = fmaf(x[i + 3], w1[i + 3], a3);
        }
        ar[j] = (a0 + a1) + (a2 + a3);
    }
#pragma unroll
    for (int c = 0; c < 4; c++) {
        uint4 v;
        v.x = f2bf_pair(ar[8 * c + 0], ar[8 * c + 1]);
        v.y = f2bf_pair(ar[8 * c + 2], ar[8 * c + 3]);
        v.z = f2bf_pair(ar[8 * c + 4], ar[8 * c + 5]);
        v.w = f2bf_pair(ar[8 * c + 6], ar[8 * c + 7]);
        Abf[(size_t)n * 4 + c] = v;
    }
    // node-MLP layer1 pos/h/u part (x[2],x[3] are zero -> harmless)
#pragma unroll 1
    for (int j = 0; j < 32; j++) {
        const float* w1 = Wf + OFF_W1NA + j * 76;
        float a0 = Wf[OFF_B1N + j], a1 = 0.f, a2 = 0.f, a3 = 0.f;
#pragma unroll
        for (int i = 0; i < 76; i += 4) {
            a0 = fmaf(x[i + 0], w1[i + 0], a0);
            a1 = fmaf(x[i + 1], w1[i + 1], a1);
            a2 = fmaf(x[i + 2], w1[i + 2], a2);
            a3 = fmaf(x[i + 3], w1[i + 3], a3);
        }
        ar[j] = (a0 + a1) + (a2 + a3);
    }
#pragma unroll
    for (int c = 0; c < 8; c++) {
        float4 v; v.x = ar[4 * c]; v.y = ar[4 * c + 1];
        v.z = ar[4 * c + 2]; v.w = ar[4 * c + 3];
        ((float4*)(A2 + (size_t)n * 32))[c] = v;
    }
}

// ---------------------------------------------------------------------------
// Pass B: one block per bucket. LDS deg/scan -> seg; LDS-cursor scatter ssrc.
// ---------------------------------------------------------------------------
__global__ __launch_bounds__(256) void k_bucketB(
    const unsigned* __restrict__ pairbuf, const int* __restrict__ gcnt,
    int2* __restrict__ seg, int* __restrict__ ssrc, int N, int C) {
    __shared__ int deg[256], scn[256], exc[256], cur[256];
    int b = blockIdx.x, tid = threadIdx.x;
    int cntb = gcnt[b];
    cntb = (cntb < C) ? cntb : C;
    deg[tid] = 0; cur[tid] = 0;
    __syncthreads();
    size_t basep = (size_t)b * C;
    for (int i = tid; i < cntb; i += 256)
        atomicAdd(&deg[pairbuf[basep + i] >> 20], 1);
    __syncthreads();
    scn[tid] = deg[tid];
    __syncthreads();
    for (int st = 1; st < 256; st <<= 1) {
        int add = (tid >= st) ? scn[tid - st] : 0;
        __syncthreads();
        scn[tid] += add;
        __syncthreads();
    }
    int ex = scn[tid] - deg[tid];
    exc[tid] = ex;
    int n = (b << BUCK_SHIFT) + tid;
    if (n < N) {
        int lo = b * C + ex;
        seg[n] = make_int2(lo, lo + deg[tid]);
    }
    __syncthreads();
    for (int i = tid; i < cntb; i += 256) {
        unsigned p = pairbuf[basep + i];
        int l = (int)(p >> 20);
        int slot = exc[l] + atomicAdd(&cur[l], 1);
        ssrc[basep + slot] = (int)(p & 0xFFFFFu);
    }
}

// ---------------------------------------------------------------------------
// Fused edge-MLP + gather: each wave owns a contiguous node range; manual
// prefetch of next batch's ssrc/Abf overlaps the dependent-load chain with
// the current batch's MFMA+tanh.
// ---------------------------------------------------------------------------
__global__ __launch_bounds__(256) void fused_edge_gather(
    const int2* __restrict__ seg, const int* __restrict__ ssrc,
    const uint4* __restrict__ Abf, const float* __restrict__ posbuf,
    const float* __restrict__ Wf, const uint4* __restrict__ fragW2,
    float* __restrict__ sumh, int N, int npw) {
    int wid = blockIdx.x * 4 + (threadIdx.x >> 6);
    int lane = threadIdx.x & 63;
    int col = lane & 15, quad = lane >> 4;

    union { uint4 u; bf16x8 v; } cvt;
    bf16x8 bfr[4];
#pragma unroll
    for (int t = 0; t < 4; t++) {
        cvt.u = fragW2[t * 64 + lane];
        bfr[t] = cvt.v;
    }
    float c0[4];
#pragma unroll
    for (int t = 0; t < 4; t++) c0[t] = Wf[OFF_B2E + 16 * t + col];
    float wx[8], wy[8];
#pragma unroll
    for (int jj = 0; jj < 8; jj++) {
        float2 wv = ((const float2*)(Wf + OFF_W1POS))[quad * 8 + jj];
        wx[jj] = wv.x; wy[jj] = wv.y;
    }

    int n0 = wid * npw;
    int n1 = n0 + npw; n1 = (n1 < N) ? n1 : N;
#pragma unroll 1
    for (int n = n0; n < n1; n++) {
        int2 sg = seg[n];
        int lo = sg.x, hi = sg.y, deg = hi - lo;
        float2 pd = ((const float2*)posbuf)[n];
        float padd[8];
#pragma unroll
        for (int jj = 0; jj < 8; jj++)
            padd[jj] = fmaf(pd.x, wx[jj], pd.y * wy[jj]);

        float po[4] = {0.f, 0.f, 0.f, 0.f};
        if (deg > 0) {
            int te = lo + col;
            te = (te < hi) ? te : (hi - 1);
            uint4 ar = Abf[(size_t)ssrc[te] * 4 + quad];
#pragma unroll 1
            for (int b = 0; b < deg; b += 16) {
                // prefetch next batch (clamped; last iter re-reads hi-1)
                int teN = lo + b + 16 + col;
                teN = (teN < hi) ? teN : (hi - 1);
                uint4 arN = Abf[(size_t)ssrc[teN] * 4 + quad];

                bf16x8 af;
                {
                    float v0 = bf_lo(ar.x) + padd[0], v1 = bf_hi(ar.x) + padd[1];
                    float v2 = bf_lo(ar.y) + padd[2], v3 = bf_hi(ar.y) + padd[3];
                    float v4 = bf_lo(ar.z) + padd[4], v5 = bf_hi(ar.z) + padd[5];
                    float v6 = bf_lo(ar.w) + padd[6], v7 = bf_hi(ar.w) + padd[7];
                    v0 = fmaxf(v0, LRELU_SLOPE * v0); v1 = fmaxf(v1, LRELU_SLOPE * v1);
                    v2 = fmaxf(v2, LRELU_SLOPE * v2); v3 = fmaxf(v3, LRELU_SLOPE * v3);
                    v4 = fmaxf(v4, LRELU_SLOPE * v4); v5 = fmaxf(v5, LRELU_SLOPE * v5);
                    v6 = fmaxf(v6, LRELU_SLOPE * v6); v7 = fmaxf(v7, LRELU_SLOPE * v7);
                    af[0] = (__bf16)v0; af[1] = (__bf16)v1; af[2] = (__bf16)v2; af[3] = (__bf16)v3;
                    af[4] = (__bf16)v4; af[5] = (__bf16)v5; af[6] = (__bf16)v6; af[7] = (__bf16)v7;
                }
                int base = b + quad * 4;
#pragma unroll
                for (int t = 0; t < 4; t++) {
                    f32x4 acc = {c0[t], c0[t], c0[t], c0[t]};
                    acc = __builtin_amdgcn_mfma_f32_16x16x32_bf16(af, bfr[t], acc, 0, 0, 0);
#pragma unroll
                    for (int r = 0; r < 4; r++) {
                        float tv = ftanh(acc[r]);
                        po[t] += (base + r < deg) ? tv : 0.f;
                    }
                }
                ar = arN;
            }
        }
#pragma unroll
        for (int t = 0; t < 4; t++) {
            po[t] += __shfl_xor(po[t], 16);
            po[t] += __shfl_xor(po[t], 32);
        }
        if (lane < 16) {
            float* sr = sumh + (size_t)n * 64;
#pragma unroll
            for (int t = 0; t < 4; t++) sr[16 * t + lane] = po[t];
        }
    }
}

// ---------------------------------------------------------------------------
// Node kernel (factored): y = A2[n] + W1NS^T . sumh[n]; o = W2n^T . lrelu(y)
// No x[138] array -> low VGPR, 4096 FMA/node.
// ---------------------------------------------------------------------------
__global__ __launch_bounds__(256) void k_node2(
    const float* __restrict__ A2, const float* __restrict__ sumh,
    const float* __restrict__ Wf, float* __restrict__ out, int N) {
    int n = blockIdx.x * blockDim.x + threadIdx.x;
    if (n >= N) return;

    float s[64];
    const float4* s4 = (const float4*)(sumh + (size_t)n * 64);
#pragma unroll
    for (int c = 0; c < 16; c++) {
        float4 v = s4[c];
        s[4 * c] = v.x; s[4 * c + 1] = v.y; s[4 * c + 2] = v.z; s[4 * c + 3] = v.w;
    }

    float o[64];
#pragma unroll
    for (int k = 0; k < 64; k++) o[k] = Wf[OFF_B2N + k];

    const float4* a24 = (const float4*)(A2 + (size_t)n * 32);
#pragma unroll 1
    for (int jj = 0; jj < 8; jj++) {
        float4 av = a24[jj];
#pragma unroll
        for (int q = 0; q < 4; q++) {
            int j = jj * 4 + q;
            const float* w1 = Wf + OFF_W1NS + j * 64;   // uniform -> s_load
            float a0 = (q == 0) ? av.x : (q == 1) ? av.y : (q == 2) ? av.z : av.w;
            float a1 = 0.f, a2 = 0.f, a3 = 0.f;
#pragma unroll
            for (int i = 0; i < 64; i += 4) {
                a0 = fmaf(s[i + 0], w1[i + 0], a0);
                a1 = fmaf(s[i + 1], w1[i + 1], a1);
                a2 = fmaf(s[i + 2], w1[i + 2], a2);
                a3 = fmaf(s[i + 3], w1[i + 3], a3);
            }
            float y = (a0 + a1) + (a2 + a3);
            y = (y >= 0.f) ? y : LRELU_SLOPE * y;
            const float* w2 = Wf + OFF_W2N + j * 64;    // uniform -> s_load
#pragma unroll
            for (int k = 0; k < 64; k++) o[k] = fmaf(y, w2[k], o[k]);
        }
    }

    float4* orow = (float4*)(out + (size_t)n * 64);
#pragma unroll
    for (int c = 0; c < 16; c++) {
        float4 v;
        v.x = ftanh(o[4 * c + 0]); v.y = ftanh(o[4 * c + 1]);
        v.z = ftanh(o[4 * c + 2]); v.w = ftanh(o[4 * c + 3]);
        orow[c] = v;
    }
}

// ---------------------------------------------------------------------------
extern "C" void kernel_launch(void* const* d_in, const int* in_sizes, int n_in,
                              void* d_out, int out_size, void* d_ws, size_t ws_size,
                              hipStream_t stream) {
    const float* hbuf   = (const float*)d_in[0];
    const float* ubuf   = (const float*)d_in[1];
    const float* posbuf = (const float*)d_in[2];
    const int* src = (const int*)d_in[3];
    const int* dst = (const int*)d_in[4];

    int N = in_sizes[0] / 64;
    int E = in_sizes[3];
    int NBUCK = (N + 255) >> BUCK_SHIFT;                 // 256-node buckets
    int C = ((2 * ((E + NBUCK - 1) / NBUCK)) + 255) & ~255;  // bucket capacity
    int nblkA = (E + 4095) / 4096;

    char* p = (char*)d_ws;
    auto alloc = [&](size_t bytes) {
        char* r = p;
        p += (bytes + 255) & ~(size_t)255;
        return r;
    };
    float*    Wf      = (float*)alloc(W_TOTAL * 4);
    uint4*    fragW2  = (uint4*)alloc(4 * 64 * 16);
    uint4*    Abf     = (uint4*)alloc((size_t)N * 64);   // bf16 A rows, 64B
    float*    A2      = (float*)alloc((size_t)N * 32 * 4);
    float*    sumh    = (float*)alloc((size_t)N * 64 * 4);
    int2*     seg     = (int2*)alloc((size_t)N * 8);
    int*      gcnt    = (int*)alloc((size_t)NBUCK * 4);
    unsigned* pairbuf = (unsigned*)alloc((size_t)NBUCK * C * 4);
    int*      ssrc    = (int*)alloc((size_t)NBUCK * C * 4);

    prep_weights<<<32, 256, 0, stream>>>(
        (const float*)d_in[5], (const float*)d_in[6],
        (const float*)d_in[7], (const float*)d_in[8],
        (const float*)d_in[9], (const float*)d_in[10],
        (const float*)d_in[11], (const float*)d_in[12], Wf, fragW2);

    hipMemsetAsync(gcnt, 0, (size_t)NBUCK * 4, stream);

    int nblkP = nblkA + (N + 255) / 256;
    k_phase1<<<nblkP, 256, 0, stream>>>(
        hbuf, ubuf, posbuf, Wf, Abf, A2, src, dst, gcnt, pairbuf, E, N, C, nblkA);

    k_bucketB<<<NBUCK, 256, 0, stream>>>(pairbuf, gcnt, seg, ssrc, N, C);

    const int FBLK = 2048;                    // 8192 waves
    int npw = (N + FBLK * 4 - 1) / (FBLK * 4);
    fused_edge_gather<<<FBLK, 256, 0, stream>>>(
        seg, ssrc, Abf, posbuf, Wf, fragW2, sumh, N, npw);

    k_node2<<<(N + 255) / 256, 256, 0, stream>>>(
        A2, sumh, Wf, (float*)d_out, N);
}